// Round 1
// baseline (292.738 us; speedup 1.0000x reference)
//
#include <hip/hip_runtime.h>
#include <stdint.h>

#define Bv 4
#define Sv 2048
#define Dv 512
#define Hv 8
#define E3 1536  // 3*D

typedef unsigned short u16;
typedef __bf16 bf16x8 __attribute__((ext_vector_type(8)));
typedef float f32x4 __attribute__((ext_vector_type(4)));

// fp32 -> bf16 RNE
__device__ __forceinline__ u16 f2b(float f) {
  union { float f; uint32_t u; } v; v.f = f;
  uint32_t r = v.u + 0x7FFFu + ((v.u >> 16) & 1u);
  return (u16)(r >> 16);
}

// async global->LDS, 16B per lane; LDS dest must be wave-uniform base (+lane*16 implicit)
__device__ __forceinline__ void gl_lds16(const void* g, void* l) {
  __builtin_amdgcn_global_load_lds(
      (__attribute__((address_space(1))) void*)(uintptr_t)g,
      (__attribute__((address_space(3))) void*)(uintptr_t)l, 16, 0, 0);
}

__global__ __launch_bounds__(256) void k_cast(const float* __restrict__ in,
                                              u16* __restrict__ out, int n8) {
  int i = blockIdx.x * 256 + threadIdx.x;
  if (i >= n8) return;
  const float4* p = (const float4*)in;
  float4 a = p[(size_t)i * 2], b = p[(size_t)i * 2 + 1];
  union { u16 h[8]; uint4 v; } r;
  r.h[0] = f2b(a.x); r.h[1] = f2b(a.y); r.h[2] = f2b(a.z); r.h[3] = f2b(a.w);
  r.h[4] = f2b(b.x); r.h[5] = f2b(b.y); r.h[6] = f2b(b.z); r.h[7] = f2b(b.w);
  ((uint4*)out)[i] = r.v;
}

// C[M][N] = A[M][K] * Bw[N][K]^T + bias, m97-style 128x128 tile, BK=32.
// OUTF32=0: bf16 out; OUTF32=1: f32 out.
template <int OUTF32>
__global__ __launch_bounds__(256) void k_gemm_bt(const u16* __restrict__ A,
                                                 const u16* __restrict__ Bw,
                                                 const float* __restrict__ bias,
                                                 void* __restrict__ C, int N, int K) {
  __shared__ alignas(16) u16 As[128][32];
  __shared__ alignas(16) u16 Bs[128][32];
  const int tid = threadIdx.x, lane = tid & 63, w = tid >> 6;
  const int quad = lane >> 4, l16 = lane & 15;
  const int wm = w & 1, wn = w >> 1;
  const size_t m0 = (size_t)blockIdx.y * 128;
  const int n0 = blockIdx.x * 128;
  const int srow = lane >> 2, scol = (lane & 3) * 8;  // staging: 16 rows/wave-issue
  f32x4 acc[4][4] = {};
  for (int k0 = 0; k0 < K; k0 += 32) {
    #pragma unroll
    for (int c = 0; c < 2; ++c) {
      const int rb = (w * 2 + c) * 16;  // wave-uniform LDS base row
      gl_lds16(A + (m0 + rb + srow) * K + k0 + scol, &As[rb][0]);
      gl_lds16(Bw + (size_t)(n0 + rb + srow) * K + k0 + scol, &Bs[rb][0]);
    }
    __syncthreads();
    bf16x8 af[4], bfr[4];
    #pragma unroll
    for (int t = 0; t < 4; ++t) {
      af[t]  = *(const bf16x8*)&As[wm * 64 + t * 16 + l16][quad * 8];
      bfr[t] = *(const bf16x8*)&Bs[wn * 64 + t * 16 + l16][quad * 8];
    }
    #pragma unroll
    for (int mt = 0; mt < 4; ++mt)
      #pragma unroll
      for (int nt = 0; nt < 4; ++nt)
        acc[mt][nt] = __builtin_amdgcn_mfma_f32_16x16x32_bf16(af[mt], bfr[nt],
                                                              acc[mt][nt], 0, 0, 0);
    __syncthreads();
  }
  // C/D layout: col = lane&15, row = quad*4 + r   [verified m89]
  #pragma unroll
  for (int nt = 0; nt < 4; ++nt) {
    const int col = n0 + wn * 64 + nt * 16 + l16;
    const float bv = bias[col];
    #pragma unroll
    for (int mt = 0; mt < 4; ++mt) {
      const size_t row = m0 + wm * 64 + mt * 16 + quad * 4;
      #pragma unroll
      for (int r = 0; r < 4; ++r) {
        float v = acc[mt][nt][r] + bv;
        if (OUTF32) ((float*)C)[(row + r) * N + col] = v;
        else        ((u16*)C)[(row + r) * N + col] = f2b(v);
      }
    }
  }
}

// v_t[b][h][dh][s] <- V rows from qkv (per 64-key tile), LDS transpose
__global__ __launch_bounds__(256) void k_vtrans(const u16* __restrict__ qkv,
                                                u16* __restrict__ vt) {
  __shared__ alignas(16) u16 T[64][72];
  const int tid = threadIdx.x;
  const int bh = blockIdx.y, b = bh >> 3, h = bh & 7;
  const int s0 = blockIdx.x * 64;
  for (int idx = tid; idx < 512; idx += 256) {
    int r = idx >> 3, c = idx & 7;
    *(uint4*)&T[r][c * 8] =
        *(const uint4*)(qkv + ((size_t)(b * Sv + s0 + r)) * E3 + h * 192 + 128 + c * 8);
  }
  __syncthreads();
  for (int idx = tid; idx < 512; idx += 256) {
    int d = idx >> 3, c = idx & 7;
    union { u16 h[8]; uint4 v; } rr;
    #pragma unroll
    for (int j = 0; j < 8; ++j) rr.h[j] = T[c * 8 + j][d];
    *(uint4*)(vt + ((size_t)(bh * 64 + d)) * Sv + s0 + c * 8) = rr.v;
  }
}

// Flash attention: BQ=64 (16 rows/wave), BKV=128, online softmax, bf16 MFMA.
__global__ __launch_bounds__(256) void k_attn(const u16* __restrict__ qkv,
                                              const u16* __restrict__ vt,
                                              const int* __restrict__ mask,
                                              u16* __restrict__ vals) {
  __shared__ alignas(16) u16 Qs[64][72];    // q rows x dh (+8 pad)
  __shared__ alignas(16) u16 Ks[128][72];   // key rows x dh
  __shared__ alignas(16) u16 Vts[64][136];  // dh rows x keys (k-major for B-frag)
  __shared__ alignas(16) u16 Ps[64][136];   // q rows x keys (A-layout for PV)
  __shared__ int msk[128];
  const int tid = threadIdx.x, lane = tid & 63, w = tid >> 6;
  const int quad = lane >> 4, l16 = lane & 15;
  const int bh = blockIdx.y, b = bh >> 3, h = bh & 7;
  const int q0 = blockIdx.x * 64;

  for (int idx = tid; idx < 512; idx += 256) {
    int r = idx >> 3, c = idx & 7;
    *(uint4*)&Qs[r][c * 8] =
        *(const uint4*)(qkv + ((size_t)(b * Sv + q0 + r)) * E3 + h * 192 + c * 8);
  }
  float m_run[4], l_run[4];
  f32x4 Oa[4] = {};
  #pragma unroll
  for (int r = 0; r < 4; ++r) { m_run[r] = -1e30f; l_run[r] = 0.f; }

  #pragma unroll 1
  for (int kt = 0; kt < Sv / 128; ++kt) {
    const int k0 = kt * 128;
    for (int idx = tid; idx < 1024; idx += 256) {
      int r = idx >> 3, c = idx & 7;
      *(uint4*)&Ks[r][c * 8] =
          *(const uint4*)(qkv + ((size_t)(b * Sv + k0 + r)) * E3 + h * 192 + 64 + c * 8);
    }
    for (int idx = tid; idx < 1024; idx += 256) {
      int d = idx >> 4, c = idx & 15;
      *(uint4*)&Vts[d][c * 8] =
          *(const uint4*)(vt + ((size_t)(bh * 64 + d)) * Sv + k0 + c * 8);
    }
    if (tid < 128) msk[tid] = mask[b * Sv + k0 + tid];
    __syncthreads();

    // S = Q K^T  (rows w*16.., 128 key cols)
    f32x4 Sa[8] = {};
    bf16x8 aq0 = *(const bf16x8*)&Qs[w * 16 + l16][quad * 8];
    bf16x8 aq1 = *(const bf16x8*)&Qs[w * 16 + l16][32 + quad * 8];
    #pragma unroll
    for (int nt = 0; nt < 8; ++nt) {
      bf16x8 bk0 = *(const bf16x8*)&Ks[nt * 16 + l16][quad * 8];
      bf16x8 bk1 = *(const bf16x8*)&Ks[nt * 16 + l16][32 + quad * 8];
      Sa[nt] = __builtin_amdgcn_mfma_f32_16x16x32_bf16(aq0, bk0, Sa[nt], 0, 0, 0);
      Sa[nt] = __builtin_amdgcn_mfma_f32_16x16x32_bf16(aq1, bk1, Sa[nt], 0, 0, 0);
    }
    // scale + key mask (finite sentinel reproduces all-masked -> uniform exactly)
    #pragma unroll
    for (int nt = 0; nt < 8; ++nt) {
      const int mk = msk[nt * 16 + l16];
      #pragma unroll
      for (int r = 0; r < 4; ++r) {
        float s = Sa[nt][r] * 0.125f;
        Sa[nt][r] = (mk == 0) ? -1e30f : s;
      }
    }
    // online softmax: row = quad*4+r, cols live on lane&15 -> reduce over 16-lane group
    float al[4];
    #pragma unroll
    for (int r = 0; r < 4; ++r) {
      float tm = Sa[0][r];
      #pragma unroll
      for (int nt = 1; nt < 8; ++nt) tm = fmaxf(tm, Sa[nt][r]);
      tm = fmaxf(tm, __shfl_xor(tm, 1));
      tm = fmaxf(tm, __shfl_xor(tm, 2));
      tm = fmaxf(tm, __shfl_xor(tm, 4));
      tm = fmaxf(tm, __shfl_xor(tm, 8));
      const float mn = fmaxf(m_run[r], tm);
      al[r] = __expf(m_run[r] - mn);
      m_run[r] = mn;
    }
    float ts[4] = {0.f, 0.f, 0.f, 0.f};
    #pragma unroll
    for (int nt = 0; nt < 8; ++nt)
      #pragma unroll
      for (int r = 0; r < 4; ++r) {
        float p = __expf(Sa[nt][r] - m_run[r]);
        Sa[nt][r] = p;
        ts[r] += p;
      }
    #pragma unroll
    for (int r = 0; r < 4; ++r) {
      ts[r] += __shfl_xor(ts[r], 1);
      ts[r] += __shfl_xor(ts[r], 2);
      ts[r] += __shfl_xor(ts[r], 4);
      ts[r] += __shfl_xor(ts[r], 8);
      l_run[r] = l_run[r] * al[r] + ts[r];
    }
    #pragma unroll
    for (int nt2 = 0; nt2 < 4; ++nt2)
      #pragma unroll
      for (int r = 0; r < 4; ++r) Oa[nt2][r] *= al[r];
    // P -> LDS (C-layout regs -> A-layout rows; each wave owns its 16 rows)
    #pragma unroll
    for (int nt = 0; nt < 8; ++nt)
      #pragma unroll
      for (int r = 0; r < 4; ++r)
        Ps[w * 16 + quad * 4 + r][nt * 16 + l16] = f2b(Sa[nt][r]);
    __syncthreads();
    // O += P * V
    #pragma unroll
    for (int ks = 0; ks < 4; ++ks) {
      bf16x8 ap = *(const bf16x8*)&Ps[w * 16 + l16][ks * 32 + quad * 8];
      #pragma unroll
      for (int nt2 = 0; nt2 < 4; ++nt2) {
        bf16x8 bv = *(const bf16x8*)&Vts[nt2 * 16 + l16][ks * 32 + quad * 8];
        Oa[nt2] = __builtin_amdgcn_mfma_f32_16x16x32_bf16(ap, bv, Oa[nt2], 0, 0, 0);
      }
    }
    __syncthreads();
  }
  #pragma unroll
  for (int r = 0; r < 4; ++r) l_run[r] = 1.0f / l_run[r];
  #pragma unroll
  for (int nt2 = 0; nt2 < 4; ++nt2)
    #pragma unroll
    for (int r = 0; r < 4; ++r) {
      const size_t srow = (size_t)(b * Sv + q0 + w * 16 + quad * 4 + r);
      vals[srow * Dv + h * 64 + nt2 * 16 + l16] = f2b(Oa[nt2][r] * l_run[r]);
    }
}

extern "C" void kernel_launch(void* const* d_in, const int* in_sizes, int n_in,
                              void* d_out, int out_size, void* d_ws, size_t ws_size,
                              hipStream_t stream) {
  const float* x    = (const float*)d_in[0];
  const int*   mask = (const int*)d_in[1];
  const float* Wqkv = (const float*)d_in[2];
  const float* bqkv = (const float*)d_in[3];
  const float* Wo   = (const float*)d_in[4];
  const float* bo   = (const float*)d_in[5];
  float* out = (float*)d_out;

  char* ws = (char*)d_ws;
  // workspace layout (bytes): total 50 MB
  u16* xb    = (u16*)(ws + 0);                    //  8,388,608  x as bf16
  u16* wqkvb = (u16*)(ws + 8388608);              //  1,572,864  W_qkv bf16
  u16* wob   = (u16*)(ws + 9961472);              //    524,288  W_o bf16
  u16* qkv   = (u16*)(ws + 10485760);             // 25,165,824  qkv bf16 [8192][1536]
  u16* vt    = (u16*)(ws + 35651584);             //  8,388,608  v_t bf16 [b][h][64][2048]
  u16* vals  = (u16*)(ws + 44040192);             //  8,388,608  attn out bf16 [8192][512]

  k_cast<<<2048, 256, 0, stream>>>(x, xb, 524288);
  k_cast<<<384, 256, 0, stream>>>(Wqkv, wqkvb, 98304);
  k_cast<<<128, 256, 0, stream>>>(Wo, wob, 32768);
  k_gemm_bt<0><<<dim3(12, 64), 256, 0, stream>>>(xb, wqkvb, bqkv, qkv, E3, Dv);
  k_vtrans<<<dim3(32, 32), 256, 0, stream>>>(qkv, vt);
  k_attn<<<dim3(32, 32), 256, 0, stream>>>(qkv, vt, mask, vals);
  k_gemm_bt<1><<<dim3(4, 64), 256, 0, stream>>>(vals, wob, bo, out, Dv, Dv);
}